// Round 6
// baseline (46.237 us; speedup 1.0000x reference)
//
#include <hip/hip_runtime.h>

// Median filter 1D, k=9, replicate padding, fp32.
// Input [B=8, C=32, L=131072] flattened: 256 rows of 131072.
//
// Layout: each block covers 4096 consecutive floats of one row as 4 chunks of
// 1024; thread t owns floats [t*4, t*4+4) of each chunk. Every load/store
// instruction is fully lane-dense (64 lanes x 16B contiguous = 1KB/wave).
// 12 independent loads issued up-front per thread (MLP), 4 dense stores.
//
// Exact median-of-9 via min3/med3/max3 triple decomposition:
//   median9(w[0..8]) = med3( max3(lo_t,lo_t3,lo_t6), med3(mi...), min3(hi...) )
// where (lo,mi,hi)[j] sort triple v[j..j+2]. Exact by rank-counting.
// Per chunk: 10 shared triple-sorts + 4 combines = 46 VOP3 ops / 4 outputs.

typedef float f32x4 __attribute__((ext_vector_type(4)));

__device__ __forceinline__ float min3f(float a, float b, float c) {
    return fminf(fminf(a, b), c);   // fuses to v_min3_f32
}
__device__ __forceinline__ float max3f(float a, float b, float c) {
    return fmaxf(fmaxf(a, b), c);   // fuses to v_max3_f32
}
__device__ __forceinline__ float med3f(float a, float b, float c) {
    return __builtin_amdgcn_fmed3f(a, b, c);
}

constexpr int kL      = 131072;        // row length (power of two)
constexpr int kTotal  = 8 * 32 * kL;   // 33,554,432 = 2^25
constexpr int kChunks = 4;
constexpr int kChunkStride = 256 * 4;  // 1024 floats between chunks
constexpr int kBlockFloats = kChunks * kChunkStride;  // 4096

__global__ __launch_bounds__(256)
void med9_f32_kernel(const float* __restrict__ in, float* __restrict__ out) {
    int tid   = threadIdx.x;
    int base0 = blockIdx.x * kBlockFloats + tid * 4;  // chunk-0 output index
    int col0  = base0 & (kL - 1);                     // chunk-0 column in row
    const float* __restrict__ rin = in + (base0 - col0);

    float v[kChunks][12];
    // Interior iff all 4 chunks' halo loads [col-4, col+8) stay inside the row.
    bool interior = (col0 >= 4) & (col0 + 3 * kChunkStride + 8 <= kL);

    if (interior) {
        // Straight-line fast path: 12 independent dense loads.
#pragma unroll
        for (int c = 0; c < kChunks; ++c) {
            int col = col0 + c * kChunkStride;
            f32x4 a = *reinterpret_cast<const f32x4*>(rin + col - 4);
            f32x4 b = *reinterpret_cast<const f32x4*>(rin + col);
            f32x4 d = *reinterpret_cast<const f32x4*>(rin + col + 4);
            v[c][0] = a.x; v[c][1] = a.y; v[c][2]  = a.z; v[c][3]  = a.w;
            v[c][4] = b.x; v[c][5] = b.y; v[c][6]  = b.z; v[c][7]  = b.w;
            v[c][8] = d.x; v[c][9] = d.y; v[c][10] = d.z; v[c][11] = d.w;
        }
    } else {
        // Row edge (512 of 2M threads): clamped scalar loads, replicate pad.
#pragma unroll
        for (int c = 0; c < kChunks; ++c) {
            int col = col0 + c * kChunkStride;
#pragma unroll
            for (int j = 0; j < 12; ++j) {
                int idx = col - 4 + j;
                idx = idx < 0 ? 0 : (idx > kL - 1 ? kL - 1 : idx);
                v[c][j] = rin[idx];
            }
        }
    }

#pragma unroll
    for (int c = 0; c < kChunks; ++c) {
        float lo[10], mi[10], hi[10];
#pragma unroll
        for (int j = 0; j < 10; ++j) {
            lo[j] = min3f(v[c][j], v[c][j + 1], v[c][j + 2]);
            mi[j] = med3f(v[c][j], v[c][j + 1], v[c][j + 2]);
            hi[j] = max3f(v[c][j], v[c][j + 1], v[c][j + 2]);
        }
        f32x4 r;
#pragma unroll
        for (int t = 0; t < 4; ++t) {
            float P = max3f(lo[t], lo[t + 3], lo[t + 6]);
            float Q = med3f(mi[t], mi[t + 3], mi[t + 6]);
            float R = min3f(hi[t], hi[t + 3], hi[t + 6]);
            ((float*)&r)[t] = med3f(P, Q, R);
        }
        *reinterpret_cast<f32x4*>(out + base0 + c * kChunkStride) = r;
    }
}

extern "C" void kernel_launch(void* const* d_in, const int* in_sizes, int n_in,
                              void* d_out, int out_size, void* d_ws, size_t ws_size,
                              hipStream_t stream) {
    const float* x = (const float*)d_in[0];
    // d_in[1] is kernel_size (==9); hardcoded (host can't read device memory
    // during graph capture).
    float* out = (float*)d_out;

    int grid = kTotal / kBlockFloats;  // 8192 blocks
    med9_f32_kernel<<<grid, 256, 0, stream>>>(x, out);
}